// Round 1
// 101.699 us; speedup vs baseline: 1.1462x; 1.1462x over previous
//
#include <hip/hip_runtime.h>
#include <math.h>

#define CC 64
#define HWN 4096
#define QB 64            // q per block = 2 wave-groups x 32
#define KSPLIT 4
#define KT 32
#define NCH (HWN / KSPLIT / KT)   // 32 chunks per wave

typedef __attribute__((ext_vector_type(8))) short bf16x8;
typedef __attribute__((ext_vector_type(4))) float f32x4;

// precomputed bf16 operand layouts (written by prep_kernel every launch)
__device__ __align__(16) unsigned short g_bgT[4][HWN][CC];  // (bg*sb)^T  [b][k][c]
__device__ __align__(16) unsigned short g_bgN[4][CC][HWN];  // bf16(bg)   [b][c][k]
__device__ __align__(16) unsigned short g_fgT[4][HWN][CC];  // (fg*sf)^T  [b][q][c]

static __device__ __forceinline__ unsigned int f2bf(float x) {   // RNE
  union { float f; unsigned int u; } v; v.f = x;
  return (v.u + 0x7fffu + ((v.u >> 16) & 1u)) >> 16;
}
static __device__ __forceinline__ unsigned int packbf(float lo, float hi) {
  return f2bf(lo) | (f2bf(hi) << 16);
}

// ---- prep: fused column norms + bf16 operand layouts ----
// grid 512 = which(2) x b(4) x ktile(64), 256 threads
__global__ __launch_bounds__(256) void prep_kernel(const float* __restrict__ bg,
                                                   const float* __restrict__ fg) {
  __shared__ float lds[64 * 65];   // [k][c], stride 65 (2-way banks everywhere)
  const int bid = blockIdx.x;
  const int kt = bid & 63, b = (bid >> 6) & 3, which = bid >> 8;
  const float* src = (which ? fg : bg) + (size_t)b * CC * HWN + kt * 64;
  const int tid = threadIdx.x;

  // stage tile transposed: thread loads [c][k-range] float4, writes lds[k][c]
  {
    int c = tid >> 2, k0 = (tid & 3) * 16;
#pragma unroll
    for (int j4 = 0; j4 < 4; ++j4) {
      float4 v = *(const float4*)(src + (size_t)c * HWN + k0 + 4 * j4);
      lds[(k0 + 4 * j4 + 0) * 65 + c] = v.x;
      lds[(k0 + 4 * j4 + 1) * 65 + c] = v.y;
      lds[(k0 + 4 * j4 + 2) * 65 + c] = v.z;
      lds[(k0 + 4 * j4 + 3) * 65 + c] = v.w;
    }
  }
  __syncthreads();

  const int k = tid >> 2, u = tid & 3;
  // column norm: 4 threads per k, each sums 16 c, combine via shfl
  float ss = 0.f;
#pragma unroll
  for (int j = 0; j < 16; ++j) {
    float v = lds[k * 65 + u * 16 + j];
    ss = fmaf(v, v, ss);
  }
  ss += __shfl_xor(ss, 1, 64);
  ss += __shfl_xor(ss, 2, 64);
  const float s = 1.0f / fmaxf(sqrtf(ss), 1e-12f);

  // write scaled transposed [b][k][c] bf16
  {
    unsigned int* gT32 = (unsigned int*)(which ? &g_fgT[0][0][0] : &g_bgT[0][0][0]);
    size_t R = (size_t)b * HWN + kt * 64 + k;
    unsigned int w8[8];
#pragma unroll
    for (int i = 0; i < 8; ++i) {
      int c2 = u * 16 + 2 * i;
      w8[i] = packbf(lds[k * 65 + c2] * s, lds[k * 65 + c2 + 1] * s);
    }
    *(uint4*)&gT32[R * 32 + u * 8]     = make_uint4(w8[0], w8[1], w8[2], w8[3]);
    *(uint4*)&gT32[R * 32 + u * 8 + 4] = make_uint4(w8[4], w8[5], w8[6], w8[7]);
  }

  // bg blocks also write raw cast [b][c][k] bf16
  if (which == 0) {
    unsigned int* gN32 = (unsigned int*)&g_bgN[0][0][0];
    int cN = tid >> 2, vN = tid & 3;
    unsigned int n8[8];
#pragma unroll
    for (int i = 0; i < 8; ++i) {
      int kk = vN * 16 + 2 * i;
      n8[i] = packbf(lds[kk * 65 + cN], lds[(kk + 1) * 65 + cN]);
    }
    size_t RN = ((size_t)b * CC + cN) * (HWN / 2) + kt * 32 + vN * 8;
    *(uint4*)&gN32[RN]     = make_uint4(n8[0], n8[1], n8[2], n8[3]);
    *(uint4*)&gN32[RN + 4] = make_uint4(n8[4], n8[5], n8[6], n8[7]);
  }
}

// ---- flash attention: bf16 MFMA, fixed-max softmax, double-buffered pipelined staging ----
// LDS: [0,32768)      staging buf0 (ks*8192: bgT 4KB + bgN 4KB, swizzled)
//      [32768,65536)  staging buf1
//      [65536,86016)  P per wave [32q][40k] ushort
//      [86016,87040)  mL [8w][32q] f32
//      merge epilogue aliases [0,34816) as mO [4ks][64c][34]
#define SMEM_BYTES 87040
__global__ __launch_bounds__(512, 2) void attn_kernel(const float* __restrict__ fg,
                                                      const float* __restrict__ mask,
                                                      float* __restrict__ out) {
  __shared__ __align__(16) char smem[SMEM_BYTES];
  const int b = blockIdx.y;
  const int q0 = blockIdx.x * QB;
  const int tid = threadIdx.x;
  const int lane = tid & 63;
  const int w = tid >> 6;     // 0..7
  const int qg = w & 1;       // q-half (32 q)
  const int ks = w >> 1;      // K-split 0..3 (1024 k each)
  const int m16 = lane & 15;
  const int quad = lane >> 4;

  // fg B-fragments, loaded once from global (L2)
  bf16x8 Bf[2][2];
  {
    int qrow = q0 + qg * 32;
#pragma unroll
    for (int qf = 0; qf < 2; ++qf)
#pragma unroll
      for (int h = 0; h < 2; ++h)
        Bf[qf][h] = *(const bf16x8*)&g_fgT[b][qrow + qf * 16 + m16][h * 32 + quad * 8];
  }

  // lane-swizzled staging sources (swizzle on global side; LDS side is lane-ordered)
  const unsigned short* srcT[2];
  const unsigned short* srcN[2];
  int offT[2];
  int offN[2];
#pragma unroll
  for (int t = 0; t < 2; ++t) {
    int ub = (t * 2 + qg) * 64;
    int uT = ub + lane;
    int kk = uT >> 3, pos = uT & 7, j = pos ^ (kk & 7);
    srcT[t] = &g_bgT[b][ks * 1024 + kk][j * 8];
    offT[t] = ks * 8192 + ub * 16;
    int uN = ub + lane;
    int cc = uN >> 2, pos4 = uN & 3, j4 = pos4 ^ ((cc >> 1) & 3);
    srcN[t] = &g_bgN[b][cc][ks * 1024 + j4 * 8];
    offN[t] = ks * 8192 + 4096 + ub * 16;
  }

  unsigned short* P = (unsigned short*)(smem + 65536 + w * 2560);  // [32 q][40 k]
  float* mL = (float*)(smem + 86016);

  float l_run[2] = {0.f, 0.f};
  f32x4 O[4][2];
#pragma unroll
  for (int t = 0; t < 4; ++t)
#pragma unroll
    for (int qf = 0; qf < 2; ++qf) O[t][qf] = (f32x4){0.f, 0.f, 0.f, 0.f};

  const int posN = quad ^ ((m16 >> 1) & 3);

  // issue staging for one chunk into smem[bufoff ..)
  auto stage = [&](int bufoff) {
#pragma unroll
    for (int t = 0; t < 2; ++t) {
      __builtin_amdgcn_global_load_lds(
          (const __attribute__((address_space(1))) unsigned int*)srcT[t],
          (__attribute__((address_space(3))) unsigned int*)(smem + bufoff + offT[t]), 16, 0, 0);
      __builtin_amdgcn_global_load_lds(
          (const __attribute__((address_space(1))) unsigned int*)srcN[t],
          (__attribute__((address_space(3))) unsigned int*)(smem + bufoff + offN[t]), 16, 0, 0);
      srcT[t] += KT * CC;   // next chunk
      srcN[t] += KT;
    }
  };

  // prologue: stage chunk 0 into buf0; __syncthreads drains vmcnt(0) so it's visible
  stage(0);
  __syncthreads();

  int bufoff = 0;
  for (int it = 0; it < NCH; ++it) {
    // issue next chunk's loads into the other buffer BEFORE compute; latency hides
    // under this iteration's MFMA+softmax. Buffer reuse is safe: buf^1 was last
    // read in iteration it-1, behind the end-of-iteration barrier.
    if (it + 1 < NCH) stage(bufoff ^ 32768);

    const char* baseT = smem + bufoff + ks * 8192;
    const char* baseN = baseT + 4096;

    // scores S[32k][32q] = (bg*sb)^T · (fg*sf)
    f32x4 S[2][2];
#pragma unroll
    for (int i = 0; i < 2; ++i) {
      int kk = 16 * i + m16;
      bf16x8 A0 = *(const bf16x8*)(baseT + kk * 128 + ((quad) ^ (kk & 7)) * 16);
      bf16x8 A1 = *(const bf16x8*)(baseT + kk * 128 + ((4 + quad) ^ (kk & 7)) * 16);
#pragma unroll
      for (int qf = 0; qf < 2; ++qf) {
        f32x4 acc = {0.f, 0.f, 0.f, 0.f};
        acc = __builtin_amdgcn_mfma_f32_16x16x32_bf16(A0, Bf[qf][0], acc, 0, 0, 0);
        acc = __builtin_amdgcn_mfma_f32_16x16x32_bf16(A1, Bf[qf][1], acc, 0, 0, 0);
        S[qf][i] = acc;
      }
    }

    // fixed-max softmax: scores are cosines, |s| <= 1 -> p = exp(s-1), no running max
#pragma unroll
    for (int qf = 0; qf < 2; ++qf) {
      float pe[2][4];
      float ps = 0.f;
#pragma unroll
      for (int i = 0; i < 2; ++i)
#pragma unroll
        for (int r = 0; r < 4; ++r) {
          pe[i][r] = __expf(S[qf][i][r] - 1.0f);
          ps += pe[i][r];
        }
      ps += __shfl_xor(ps, 16, 64);
      ps += __shfl_xor(ps, 32, 64);
      l_run[qf] += ps;
      // pack P -> per-wave LDS [q][k] bf16 (round-half-up via +0x8000, v_perm pack)
#pragma unroll
      for (int i = 0; i < 2; ++i) {
        union { float f; unsigned int u; } x0, x1, x2, x3;
        x0.f = pe[i][0]; x1.f = pe[i][1]; x2.f = pe[i][2]; x3.f = pe[i][3];
        unsigned int p01 = __builtin_amdgcn_perm(x1.u + 0x8000u, x0.u + 0x8000u, 0x07060302u);
        unsigned int p23 = __builtin_amdgcn_perm(x3.u + 0x8000u, x2.u + 0x8000u, 0x07060302u);
        *(uint2*)&P[(qf * 16 + m16) * 40 + 16 * i + quad * 4] = make_uint2(p01, p23);
      }
    }

    // PV: O[c][q] += bg[c][k] · P[k][q]   (per-wave P: no barrier needed)
    bf16x8 Pf0 = *(const bf16x8*)&P[m16 * 40 + quad * 8];
    bf16x8 Pf1 = *(const bf16x8*)&P[(16 + m16) * 40 + quad * 8];
#pragma unroll
    for (int t = 0; t < 4; ++t) {
      int c = 16 * t + m16;
      bf16x8 A = *(const bf16x8*)(baseN + c * 64 + posN * 16);
      O[t][0] = __builtin_amdgcn_mfma_f32_16x16x32_bf16(A, Pf0, O[t][0], 0, 0, 0);
      O[t][1] = __builtin_amdgcn_mfma_f32_16x16x32_bf16(A, Pf1, O[t][1], 0, 0, 0);
    }

    // single barrier per chunk: compiler drains vmcnt(0) (my it+1 loads done) and
    // lgkmcnt(0) (my buf reads done) before s_barrier -> next iteration is safe.
    __syncthreads();
    bufoff ^= 32768;
  }

  // ---- merge 4 K-splits + epilogue (two q-half passes; mO aliases staging LDS) ----
  if (quad == 0) {
    mL[w * 32 + m16] = l_run[0];
    mL[w * 32 + 16 + m16] = l_run[1];
  }
  float* mO = (float*)smem;   // [4 ks][64 c][34]
  const float* fgB = fg + (size_t)b * CC * HWN;
  const float* mk = mask + (size_t)b * HWN;
  float* outB = out + (size_t)b * CC * HWN;

#pragma unroll
  for (int half = 0; half < 2; ++half) {
    __syncthreads();
    if (qg == half) {
#pragma unroll
      for (int t = 0; t < 4; ++t)
#pragma unroll
        for (int qf = 0; qf < 2; ++qf)
#pragma unroll
          for (int r = 0; r < 4; ++r)
            mO[(ks * 64 + 16 * t + quad * 4 + r) * 34 + qf * 16 + m16] = O[t][qf][r];
    }
    __syncthreads();
    {
      int q = tid & 31, cb = tid >> 5;   // cb 0..15
      int qglob = q0 + half * 32 + q;
      float L = mL[(0 * 2 + half) * 32 + q] + mL[(1 * 2 + half) * 32 + q] +
                mL[(2 * 2 + half) * 32 + q] + mL[(3 * 2 + half) * 32 + q];
      float invL = 1.0f / L;
      float mv = mk[qglob];
#pragma unroll
      for (int e = 0; e < 4; ++e) {
        int c = cb * 4 + e;
        float acc = mO[(0 * 64 + c) * 34 + q] + mO[(1 * 64 + c) * 34 + q] +
                    mO[(2 * 64 + c) * 34 + q] + mO[(3 * 64 + c) * 34 + q];
        float att = acc * invL;
        float fgv = fgB[(size_t)c * HWN + qglob];
        outB[(size_t)c * HWN + qglob] = fgv + mv * (att - fgv);
      }
    }
  }
}

extern "C" void kernel_launch(void* const* d_in, const int* in_sizes, int n_in,
                              void* d_out, int out_size, void* d_ws, size_t ws_size,
                              hipStream_t stream) {
  const float* background = (const float*)d_in[0];
  const float* foreground = (const float*)d_in[1];
  const float* mask       = (const float*)d_in[2];
  float* out = (float*)d_out;
  prep_kernel<<<512, 256, 0, stream>>>(background, foreground);
  attn_kernel<<<dim3(HWN / QB, 4), 512, 0, stream>>>(foreground, mask, out);
}